// Round 12
// baseline (248.600 us; speedup 1.0000x reference)
//
#include <hip/hip_runtime.h>
#include <stdint.h>

#define BB 32
#define CC 2048
#define NPIX 49
#define KPAD 64
#define K9 18432      // CC*9 (k = tap*2048 + ci, tap-major)
#define ZROWS 2624    // 32*81 interior+halo rows + 32 guard rows (zero)
#define NP 1792       // dense n padded (14*128)
#define CONV_SPLITK 4

typedef __bf16 bf16;
typedef __bf16 bf16x2 __attribute__((ext_vector_type(2)));
typedef __bf16 bf16x4 __attribute__((ext_vector_type(4)));
typedef __bf16 bf16x8 __attribute__((ext_vector_type(8)));
typedef float f32x4 __attribute__((ext_vector_type(4)));
typedef uint32_t u32x4 __attribute__((ext_vector_type(4)));

#define MFMA(a,b,c) __builtin_amdgcn_mfma_f32_16x16x32_bf16(a,b,c,0,0,0)
#define GLOAD_LDS(g, l) __builtin_amdgcn_global_load_lds( \
    (const __attribute__((address_space(1))) void*)(g),   \
    (__attribute__((address_space(3))) void*)(l), 16, 0, 0)

// ---------- fused prep: x -> xb [B][C][64] AND xbT [B][64][C] (reads x once) ----------
__global__ void prep_fused_kernel(const float* __restrict__ x,
                                  bf16* __restrict__ xb, bf16* __restrict__ xbT) {
    __shared__ float xt[6272];   // 128*49
    const int tid = threadIdx.x;
    const int b = blockIdx.x >> 4, cb = blockIdx.x & 15;
    const float* src = x + ((size_t)(b * 2048 + cb * 128)) * 49;
#pragma unroll
    for (int i = 0; i < 25; i++) {
        int idx = i * 256 + tid;
        if (idx < 6272) xt[idx] = src[idx];
    }
    __syncthreads();
    {
        const int r = tid >> 1, h = tid & 1;
        bf16* dst = xb + ((size_t)(b * 2048 + cb * 128 + r)) * 64 + h * 32;
        const float* row = &xt[r * 49];
#pragma unroll
        for (int v = 0; v < 4; v++) {
            bf16x8 o;
#pragma unroll
            for (int e = 0; e < 8; e++) {
                int n = h * 32 + v * 8 + e;
                o[e] = (bf16)(n < 49 ? row[n] : 0.f);
            }
            *(bf16x8*)(dst + v * 8) = o;
        }
    }
    {
        const int n = tid >> 2, q = tid & 3;
        bf16* dst = xbT + ((size_t)b * 64 + n) * 2048 + cb * 128 + q * 32;
#pragma unroll
        for (int v = 0; v < 4; v++) {
            bf16x8 o;
#pragma unroll
            for (int e = 0; e < 8; e++) {
                int cl = q * 32 + v * 8 + e;
                o[e] = (bf16)(n < 49 ? xt[cl * 49 + n] : 0.f);
            }
            *(bf16x8*)(dst + v * 8) = o;
        }
    }
}

// ---------- prep: conv_w [co][ci][3][3] f32 -> Wr [co][t][ci] bf16 ----------
__global__ void castw_kernel(const float* __restrict__ cw, bf16* __restrict__ Wr) {
    uint32_t t = blockIdx.x * 256u + threadIdx.x;
    uint32_t q = t & 511u, co = t >> 9;
    uint32_t ci0 = q * 4u;
    const float* src = cw + ((size_t)co * 2048u + ci0) * 9u;
    float v[4][9];
#pragma unroll
    for (int c = 0; c < 4; c++)
#pragma unroll
        for (int tt = 0; tt < 9; tt++) v[c][tt] = src[c * 9 + tt];
    bf16* dst = Wr + (size_t)co * K9 + ci0;
#pragma unroll
    for (int tt = 0; tt < 9; tt++) {
        bf16x4 o;
        o[0] = (bf16)v[0][tt]; o[1] = (bf16)v[1][tt];
        o[2] = (bf16)v[2][tt]; o[3] = (bf16)v[3][tt];
        *(bf16x4*)(dst + (size_t)tt * 2048u) = o;
    }
}

// ---------- prep: zero YpT ----------
__global__ void zero_ypt_kernel(u32x4* __restrict__ YpT) {
    YpT[blockIdx.x * 256u + threadIdx.x] = (u32x4){0, 0, 0, 0};
}

// ---------- fused bilinear -> softmax -> Y: 8 waves x 16 c-rows (R11, unchanged) ----------
__global__ __launch_bounds__(512, 2) void attn_kernel(
    const bf16* __restrict__ xb, const bf16* __restrict__ xbT, bf16* __restrict__ YpT)
{
    __shared__ __align__(16) char smem[67584];
    bf16* Ktile = (bf16*)smem;                         // [128 d][64 k]   swizzled
    bf16* Vtile = (bf16*)(smem + 16384);               // [64 n][128 d]   swizzled
    bf16 (*Plds)[16][136] = reinterpret_cast<bf16(*)[16][136]>(smem + 32768);
    bf16 (*Tlds)[132] = reinterpret_cast<bf16(*)[132]>(smem);

    const int tid = threadIdx.x;
    const int w = tid >> 6, l = tid & 63;
    const int lhi = l >> 4, llo = l & 15;
    const uint32_t g = blockIdx.x;
    const int xcd = g & 7, inner = g >> 3;
    const int b = xcd + (inner >> 4) * 8;
    const int cblk = inner & 15;
    const int c0 = cblk * 128 + w * 16;
    const bf16* xbB = xb + (size_t)b * CC * KPAD;
    const bf16* xbTB = xbT + (size_t)b * KPAD * CC;

    bf16x8 aQ[2];
#pragma unroll
    for (int kk = 0; kk < 2; kk++)
        aQ[kk] = *(const bf16x8*)(xbB + (uint32_t)(c0 + llo) * KPAD + kk * 32 + lhi * 8);

    const uint32_t rowK = tid >> 3;
    const uint32_t srcKoff = (uint32_t)(((tid & 7u) ^ (rowK & 7u)) << 3);
    const bf16* kSrc = xbB + (size_t)rowK * KPAD + srcKoff;
    const uint32_t rowV = tid >> 4;
    const uint32_t srcVoff = (uint32_t)(((tid & 15u) ^ (rowV & 7u)) << 3);
    const bf16* vSrc = xbTB + (size_t)rowV * CC + srcVoff;

    f32x4 accY[4];
#pragma unroll
    for (int nf = 0; nf < 4; nf++) accY[nf] = (f32x4){0, 0, 0, 0};
    float rowsum[4] = {};

    const float kES = -0.029442756956917622f;          // -log2(e)/49

    for (int dt = 0; dt < 16; dt++) {
        const int d0 = dt * 128;
#pragma unroll
        for (int i = 0; i < 2; i++) {
            GLOAD_LDS(kSrc + (size_t)(d0 + i * 64) * KPAD, (char*)Ktile + i * 8192 + tid * 16);
            GLOAD_LDS(vSrc + d0 + (size_t)i * 32 * CC,     (char*)Vtile + i * 8192 + tid * 16);
        }
        __syncthreads();

        f32x4 accS[8];
#pragma unroll
        for (int df = 0; df < 8; df++) accS[df] = (f32x4){0, 0, 0, 0};
#pragma unroll
        for (int kk = 0; kk < 2; kk++) {
#pragma unroll
            for (int df = 0; df < 8; df++) {
                uint32_t r = (uint32_t)(df * 16 + llo);
                bf16x8 bK = *(const bf16x8*)((const char*)Ktile + r * 128u +
                                             ((((uint32_t)(kk * 4 + lhi)) ^ (r & 7u)) << 4));
                accS[df] = MFMA(aQ[kk], bK, accS[df]);
            }
        }
#pragma unroll
        for (int df = 0; df < 8; df++)
#pragma unroll
            for (int r = 0; r < 4; r++) {
                float p = __builtin_amdgcn_exp2f(accS[df][r] * kES);
                rowsum[r] += p;
                Plds[w][lhi * 4 + r][df * 16 + llo] = (bf16)p;
            }
#pragma unroll
        for (int kk2 = 0; kk2 < 4; kk2++) {
            bf16x8 aP = *(const bf16x8*)&Plds[w][llo][kk2 * 32 + lhi * 8];
#pragma unroll
            for (int nf = 0; nf < 4; nf++) {
                uint32_t r = (uint32_t)(nf * 16 + llo);
                bf16x8 bV = *(const bf16x8*)((const char*)Vtile + r * 256u +
                                             ((((uint32_t)(kk2 * 4 + lhi)) ^ (r & 7u)) << 4));
                accY[nf] = MFMA(aP, bV, accY[nf]);
            }
        }
        __syncthreads();
    }
#pragma unroll
    for (int r = 0; r < 4; r++) {
        float s = rowsum[r];
        s += __shfl_xor(s, 1);
        s += __shfl_xor(s, 2);
        s += __shfl_xor(s, 4);
        s += __shfl_xor(s, 8);
        rowsum[r] = 1.0f / s;
    }
    __syncthreads();
#pragma unroll
    for (int nf = 0; nf < 4; nf++)
#pragma unroll
        for (int r = 0; r < 4; r++) {
            int n = nf * 16 + llo;
            int cl = w * 16 + lhi * 4 + r;
            Tlds[n][cl] = (bf16)(accY[nf][r] * rowsum[r]);
        }
    __syncthreads();
#pragma unroll
    for (int rr = 0; rr < 7; rr++) {
        int row = rr * 8 + w;
        if (row < NPIX) {
            int i = row / 7, j = row % 7;
            int sp = (i + 1) * 9 + (j + 1);
            int col2 = tid & 63;
            uint32_t val = *(const uint32_t*)&Tlds[row][col2 * 2];
            *(uint32_t*)(YpT + ((size_t)b * 81 + sp) * CC + cblk * 128 + col2 * 2) = val;
        }
    }
}

// ---------- conv GEMM: 256x256, BK=64, m201-style 2-barrier phases, pre-barrier reads ----------
// Phase p: [reads(p); stage(half p+3); BAR_L; lgkm0; MFMA; VMW(gate); BAR_T].
// Gate VMW(4) at p's tail retires stage(p-2) = half read at p+1 -> reads(p+1) pre-BAR safe.
// Prologue VMW(8) retires H0. Peel gates: ...,4,4,0,none.
#define CONV_SB() __builtin_amdgcn_sched_barrier(0)
#define CONV_BAR() do { CONV_SB(); __builtin_amdgcn_s_barrier(); CONV_SB(); } while (0)
#define CONV_VMW(n) asm volatile("s_waitcnt vmcnt(" #n ")" ::: "memory")

#define STAGE_HALF(bufOff, t, kh) do {                                         \
    uint32_t kt_ = z * 72u + (uint32_t)(t);                                    \
    uint32_t tap_ = kt_ >> 5, ci0_ = (kt_ & 31u) << 6;                         \
    int tapoff_ = (int)(tap_ / 3u) * 9 + (int)(tap_ % 3u) - 10;                \
    uint32_t kA_ = (uint32_t)(t) * 64u + (uint32_t)(kh) * 32u;                 \
    _Pragma("unroll")                                                          \
    for (int i_ = 0; i_ < 2; i_++) {                                           \
        GLOAD_LDS(srcA[i_] + kA_,                                              \
                  smem + (bufOff) + (kh) * 16384 + i_ * 8192 + tid * 16);      \
        GLOAD_LDS(srcB[i_] + (int)(ci0_ + (uint32_t)(kh) * 32u) + tapoff_ * 2048, \
                  smem + (bufOff) + 32768 + (kh) * 16384 + i_ * 8192 + tid * 16); \
    }                                                                          \
} while (0)

#define CONV_MFMA_BODY(bufOff, kk)                                             \
    bf16x8 af[8], bfr[4];                                                      \
    _Pragma("unroll")                                                          \
    for (int f = 0; f < 8; f++)                                                \
        af[f] = *(const bf16x8*)(smem + (bufOff) + (kk) * 16384 + offA[f]);    \
    _Pragma("unroll")                                                          \
    for (int f = 0; f < 4; f++)                                                \
        bfr[f] = *(const bf16x8*)(smem + (bufOff) + 32768 + (kk) * 16384 + offB[f]);

#define CONV_MFMA_EXEC() do {                                                  \
    asm volatile("s_waitcnt lgkmcnt(0)" ::: "memory");                         \
    CONV_SB();                                                                 \
    __builtin_amdgcn_s_setprio(1);                                             \
    _Pragma("unroll")                                                          \
    for (int fm = 0; fm < 8; fm++)                                             \
        _Pragma("unroll")                                                      \
        for (int fn = 0; fn < 4; fn++)                                         \
            acc[fm][fn] = MFMA(af[fm], bfr[fn], acc[fm][fn]);                  \
    __builtin_amdgcn_s_setprio(0);                                             \
    CONV_SB();                                                                 \
} while (0)

#define CONV_PHASE(bufOff, kk, STAGE_STMT, GATE) do {                          \
    CONV_MFMA_BODY(bufOff, kk)                                                 \
    STAGE_STMT;                                                                \
    CONV_BAR();                       /* BAR_L: schedule region split */       \
    CONV_MFMA_EXEC();                                                          \
    CONV_VMW(GATE);                                                            \
    CONV_BAR();                       /* BAR_T: certify half for p+1 */        \
} while (0)

#define CONV_PHASE_LAST(bufOff, kk) do {                                       \
    CONV_MFMA_BODY(bufOff, kk)                                                 \
    CONV_BAR();                                                                \
    CONV_MFMA_EXEC();                                                          \
} while (0)

__global__ __launch_bounds__(512, 2) void conv_kernel(
    const bf16* __restrict__ Wr, const bf16* __restrict__ YpT, float* __restrict__ partials)
{
    extern __shared__ __align__(16) char smem[];
    const int tid = threadIdx.x;
    const int w = tid >> 6, l = tid & 63;
    const int lhi = l >> 4, llo = l & 15;
    const int wm = w >> 2, wn = w & 3;           // wave owns 128co x 64n

    uint32_t g = blockIdx.x;
    uint32_t xcd = g & 7u, inner = g >> 3;       // inner in [0,28)
    uint32_t pairIdx = xcd * 4u + inner / 7u;    // [0,32): (z,mt) grouped per XCD
    uint32_t nt = inner % 7u;
    uint32_t z = pairIdx >> 3, mt = pairIdx & 7u;

    // staging source (pre-swizzled to match read swizzle slot ^ ((row>>1)&3))
    uint32_t rowLoc = tid >> 2;                  // [0,128)
    uint32_t slot = tid & 3u;
    const bf16* srcA[2];
    const bf16* srcB[2];
#pragma unroll
    for (int i = 0; i < 2; i++) {
        uint32_t row = (uint32_t)i * 128u + rowLoc;
        uint32_t swz = (uint32_t)((slot ^ ((row >> 1) & 3u)) << 3);
        srcA[i] = Wr + (size_t)(mt * 256u + row) * K9 + (size_t)z * 4608u + swz;
        uint32_t n = nt * 256u + row;
        uint32_t rowIdx;
        if (n < 1568u) {
            uint32_t b = n / 49u, p = n % 49u;
            uint32_t i2 = p / 7u, j2 = p % 7u;
            rowIdx = b * 81u + (i2 + 1u) * 9u + (j2 + 1u);
        } else rowIdx = 2602u;
        srcB[i] = YpT + (size_t)rowIdx * 2048u + swz;
    }

    // ds_read fragment offsets (swizzled, loop-invariant)
    uint32_t offA[8], offB[4];
#pragma unroll
    for (int f = 0; f < 8; f++) {
        uint32_t r = (uint32_t)(wm * 128 + f * 16 + llo);
        offA[f] = r * 64u + (uint32_t)(((uint32_t)lhi ^ ((r >> 1) & 3u)) << 4);
    }
#pragma unroll
    for (int f = 0; f < 4; f++) {
        uint32_t r = (uint32_t)(wn * 64 + f * 16 + llo);
        offB[f] = r * 64u + (uint32_t)(((uint32_t)lhi ^ ((r >> 1) & 3u)) << 4);
    }

    f32x4 acc[8][4];
#pragma unroll
    for (int fm = 0; fm < 8; fm++)
#pragma unroll
        for (int fn = 0; fn < 4; fn++) acc[fm][fn] = (f32x4){0, 0, 0, 0};

    // prologue: H0=buf0.k0(T0), H1=buf0.k1(T0), H2=buf1.k0(T1); certify H0
    STAGE_HALF(0, 0, 0);
    STAGE_HALF(0, 0, 1);
    STAGE_HALF(65536, 1, 0);
    CONV_VMW(8);
    CONV_BAR();

    for (int it = 0; it < 35; ++it) {
        const int t0 = it * 2;
        CONV_PHASE(0,     0, STAGE_HALF(65536, t0 + 1, 1), 4);
        CONV_PHASE(0,     1, STAGE_HALF(0,     t0 + 2, 0), 4);
        CONV_PHASE(65536, 0, STAGE_HALF(0,     t0 + 2, 1), 4);
        CONV_PHASE(65536, 1, STAGE_HALF(65536, t0 + 3, 0), 4);
    }
    // peeled phases 140..143 (tiles 70, 71); gates 4,4,0,none
    CONV_PHASE(0,     0, STAGE_HALF(65536, 71, 1), 4);
    CONV_PHASE(0,     1, (void)0,                  4);
    CONV_PHASE(65536, 0, (void)0,                  0);
    CONV_PHASE_LAST(65536, 1);

    float* pz = partials + (size_t)z * 2048u * NP;
    uint32_t co0 = mt * 256u + (uint32_t)(wm * 128 + lhi * 4);
    uint32_t n0 = nt * 256u + (uint32_t)(wn * 64 + llo);
#pragma unroll
    for (int fm = 0; fm < 8; fm++)
#pragma unroll
        for (int fn = 0; fn < 4; fn++)
#pragma unroll
            for (int r = 0; r < 4; r++)
                pz[(size_t)(co0 + fm * 16u + r) * NP + (n0 + fn * 16u)] = acc[fm][fn][r];
}

// ---------- reduce: out = sum_z partials + bias + residual ----------
__global__ void reduce_kernel(const float* __restrict__ partials, const float* __restrict__ x,
                              const float* __restrict__ cb, float* __restrict__ out)
{
    uint32_t idx = blockIdx.x * 256u + threadIdx.x;
    uint32_t p = idx % 49u;
    uint32_t c = (idx / 49u) & 2047u;
    uint32_t b = idx / (49u * 2048u);
    uint32_t n = b * 49u + p;
    size_t base = (size_t)c * NP + n;
    float s = cb[c] + x[idx];
#pragma unroll
    for (int zz = 0; zz < CONV_SPLITK; zz++) s += partials[(size_t)zz * 2048u * NP + base];
    out[idx] = s;
}

extern "C" void kernel_launch(void* const* d_in, const int* in_sizes, int n_in,
                              void* d_out, int out_size, void* d_ws, size_t ws_size,
                              hipStream_t stream) {
    (void)in_sizes; (void)n_in; (void)out_size; (void)ws_size;
    const float* x = (const float*)d_in[0];
    const float* cw = (const float*)d_in[1];
    const float* cb = (const float*)d_in[2];
    float* out = (float*)d_out;
    char* ws = (char*)d_ws;

    bf16* xb   = (bf16*)(ws);                    //   8,388,608 B
    bf16* xbT  = (bf16*)(ws + 8388608);          //   8,388,608 B
    bf16* Wr   = (bf16*)(ws + 16777216);         //  75,497,472 B
    bf16* YpT  = (bf16*)(ws + 92274688);         //  10,747,904 B
    float* partials = (float*)(ws + 103022592);  //  58,720,256 B (total 161,742,848)

    hipFuncSetAttribute((const void*)conv_kernel,
                        hipFuncAttributeMaxDynamicSharedMemorySize, 131072);

    prep_fused_kernel<<<512, 256, 0, stream>>>(x, xb, xbT);
    castw_kernel<<<4096, 256, 0, stream>>>(cw, Wr);
    zero_ypt_kernel<<<2624, 256, 0, stream>>>((u32x4*)YpT);
    attn_kernel<<<512, 512, 0, stream>>>(xb, xbT, YpT);
    conv_kernel<<<224, 512, 131072, stream>>>(Wr, YpT, partials);
    reduce_kernel<<<12544, 256, 0, stream>>>(partials, x, cb, out);
}

// Round 13
// 236.576 us; speedup vs baseline: 1.0508x; 1.0508x over previous
//
#include <hip/hip_runtime.h>
#include <stdint.h>

#define BB 32
#define CC 2048
#define NPIX 49
#define KPAD 64
#define K9 18432      // CC*9 (k = tap*2048 + ci, tap-major)
#define ZROWS 2624    // 32*81 interior+halo rows + 32 guard rows (zero)
#define NP 1792       // dense n padded (14*128)
#define CONV_SPLITK 4

typedef __bf16 bf16;
typedef __bf16 bf16x2 __attribute__((ext_vector_type(2)));
typedef __bf16 bf16x4 __attribute__((ext_vector_type(4)));
typedef __bf16 bf16x8 __attribute__((ext_vector_type(8)));
typedef float f32x4 __attribute__((ext_vector_type(4)));
typedef uint32_t u32x4 __attribute__((ext_vector_type(4)));

#define MFMA(a,b,c) __builtin_amdgcn_mfma_f32_16x16x32_bf16(a,b,c,0,0,0)
#define GLOAD_LDS(g, l) __builtin_amdgcn_global_load_lds( \
    (const __attribute__((address_space(1))) void*)(g),   \
    (__attribute__((address_space(3))) void*)(l), 16, 0, 0)

// ---------- fused prep: x -> xb [B][C][64] AND xbT [B][64][C] (reads x once) ----------
__global__ void prep_fused_kernel(const float* __restrict__ x,
                                  bf16* __restrict__ xb, bf16* __restrict__ xbT) {
    __shared__ float xt[6272];   // 128*49
    const int tid = threadIdx.x;
    const int b = blockIdx.x >> 4, cb = blockIdx.x & 15;
    const float* src = x + ((size_t)(b * 2048 + cb * 128)) * 49;
#pragma unroll
    for (int i = 0; i < 25; i++) {
        int idx = i * 256 + tid;
        if (idx < 6272) xt[idx] = src[idx];
    }
    __syncthreads();
    {
        const int r = tid >> 1, h = tid & 1;
        bf16* dst = xb + ((size_t)(b * 2048 + cb * 128 + r)) * 64 + h * 32;
        const float* row = &xt[r * 49];
#pragma unroll
        for (int v = 0; v < 4; v++) {
            bf16x8 o;
#pragma unroll
            for (int e = 0; e < 8; e++) {
                int n = h * 32 + v * 8 + e;
                o[e] = (bf16)(n < 49 ? row[n] : 0.f);
            }
            *(bf16x8*)(dst + v * 8) = o;
        }
    }
    {
        const int n = tid >> 2, q = tid & 3;
        bf16* dst = xbT + ((size_t)b * 64 + n) * 2048 + cb * 128 + q * 32;
#pragma unroll
        for (int v = 0; v < 4; v++) {
            bf16x8 o;
#pragma unroll
            for (int e = 0; e < 8; e++) {
                int cl = q * 32 + v * 8 + e;
                o[e] = (bf16)(n < 49 ? xt[cl * 49 + n] : 0.f);
            }
            *(bf16x8*)(dst + v * 8) = o;
        }
    }
}

// ---------- prep: conv_w [co][ci][3][3] f32 -> Wr [co][t][ci] bf16 (f32x4 reads) ----------
__global__ void castw_kernel(const float* __restrict__ cw, bf16* __restrict__ Wr) {
    uint32_t t = blockIdx.x * 256u + threadIdx.x;   // 2048*512
    uint32_t q = t & 511u, co = t >> 9;
    uint32_t ci0 = q * 4u;
    const f32x4* src4 = (const f32x4*)(cw + ((size_t)co * 2048u + ci0) * 9u);  // 16B aligned
    float v[36];
#pragma unroll
    for (int m = 0; m < 9; m++) {
        f32x4 t4 = src4[m];
#pragma unroll
        for (int e = 0; e < 4; e++) v[m * 4 + e] = t4[e];
    }
    bf16* dst = Wr + (size_t)co * K9 + ci0;
#pragma unroll
    for (int tt = 0; tt < 9; tt++) {
        bf16x4 o;
        o[0] = (bf16)v[0 * 9 + tt]; o[1] = (bf16)v[1 * 9 + tt];
        o[2] = (bf16)v[2 * 9 + tt]; o[3] = (bf16)v[3 * 9 + tt];
        *(bf16x4*)(dst + (size_t)tt * 2048u) = o;
    }
}

// ---------- fused bilinear -> softmax -> Y: 8 waves x 16 c-rows; halo-zero folded in ----------
__global__ __launch_bounds__(512, 2) void attn_kernel(
    const bf16* __restrict__ xb, const bf16* __restrict__ xbT, bf16* __restrict__ YpT)
{
    __shared__ __align__(16) char smem[67584];
    bf16* Ktile = (bf16*)smem;                         // [128 d][64 k]   swizzled
    bf16* Vtile = (bf16*)(smem + 16384);               // [64 n][128 d]   swizzled
    bf16 (*Plds)[16][136] = reinterpret_cast<bf16(*)[16][136]>(smem + 32768);
    bf16 (*Tlds)[132] = reinterpret_cast<bf16(*)[132]>(smem);

    const int tid = threadIdx.x;
    const int w = tid >> 6, l = tid & 63;
    const int lhi = l >> 4, llo = l & 15;
    const uint32_t g = blockIdx.x;
    const int xcd = g & 7, inner = g >> 3;
    const int b = xcd + (inner >> 4) * 8;
    const int cblk = inner & 15;
    const int c0 = cblk * 128 + w * 16;
    const bf16* xbB = xb + (size_t)b * CC * KPAD;
    const bf16* xbTB = xbT + (size_t)b * KPAD * CC;

    // folded zero_ypt: zero this block's 128-col slice of its batch's 32 halo rows
    // (b==0 blocks also zero the 32 guard rows). conv runs after attn -> no hazard.
    {
        int h = tid >> 4, c16 = tid & 15;
        int row;
        if (h < 9) row = h;                        // top halo 0..8
        else if (h < 18) row = 63 + h;             // bottom halo 72..80
        else { int p = h - 18; row = 9 * ((p >> 1) + 1) + (p & 1) * 8; }  // side halos
        u32x4 z4 = {0, 0, 0, 0};
        *(u32x4*)(YpT + ((size_t)b * 81 + row) * CC + cblk * 128 + c16 * 8) = z4;
        if (b == 0)
            *(u32x4*)(YpT + (size_t)(2592 + h) * CC + cblk * 128 + c16 * 8) = z4;
    }

    bf16x8 aQ[2];
#pragma unroll
    for (int kk = 0; kk < 2; kk++)
        aQ[kk] = *(const bf16x8*)(xbB + (uint32_t)(c0 + llo) * KPAD + kk * 32 + lhi * 8);

    const uint32_t rowK = tid >> 3;
    const uint32_t srcKoff = (uint32_t)(((tid & 7u) ^ (rowK & 7u)) << 3);
    const bf16* kSrc = xbB + (size_t)rowK * KPAD + srcKoff;
    const uint32_t rowV = tid >> 4;
    const uint32_t srcVoff = (uint32_t)(((tid & 15u) ^ (rowV & 7u)) << 3);
    const bf16* vSrc = xbTB + (size_t)rowV * CC + srcVoff;

    f32x4 accY[4];
#pragma unroll
    for (int nf = 0; nf < 4; nf++) accY[nf] = (f32x4){0, 0, 0, 0};
    float rowsum[4] = {};

    const float kES = -0.029442756956917622f;          // -log2(e)/49

    for (int dt = 0; dt < 16; dt++) {
        const int d0 = dt * 128;
#pragma unroll
        for (int i = 0; i < 2; i++) {
            GLOAD_LDS(kSrc + (size_t)(d0 + i * 64) * KPAD, (char*)Ktile + i * 8192 + tid * 16);
            GLOAD_LDS(vSrc + d0 + (size_t)i * 32 * CC,     (char*)Vtile + i * 8192 + tid * 16);
        }
        __syncthreads();

        f32x4 accS[8];
#pragma unroll
        for (int df = 0; df < 8; df++) accS[df] = (f32x4){0, 0, 0, 0};
#pragma unroll
        for (int kk = 0; kk < 2; kk++) {
#pragma unroll
            for (int df = 0; df < 8; df++) {
                uint32_t r = (uint32_t)(df * 16 + llo);
                bf16x8 bK = *(const bf16x8*)((const char*)Ktile + r * 128u +
                                             ((((uint32_t)(kk * 4 + lhi)) ^ (r & 7u)) << 4));
                accS[df] = MFMA(aQ[kk], bK, accS[df]);
            }
        }
#pragma unroll
        for (int df = 0; df < 8; df++)
#pragma unroll
            for (int r = 0; r < 4; r++) {
                float p = __builtin_amdgcn_exp2f(accS[df][r] * kES);
                rowsum[r] += p;
                Plds[w][lhi * 4 + r][df * 16 + llo] = (bf16)p;
            }
#pragma unroll
        for (int kk2 = 0; kk2 < 4; kk2++) {
            bf16x8 aP = *(const bf16x8*)&Plds[w][llo][kk2 * 32 + lhi * 8];
#pragma unroll
            for (int nf = 0; nf < 4; nf++) {
                uint32_t r = (uint32_t)(nf * 16 + llo);
                bf16x8 bV = *(const bf16x8*)((const char*)Vtile + r * 256u +
                                             ((((uint32_t)(kk2 * 4 + lhi)) ^ (r & 7u)) << 4));
                accY[nf] = MFMA(aP, bV, accY[nf]);
            }
        }
        __syncthreads();
    }
#pragma unroll
    for (int r = 0; r < 4; r++) {
        float s = rowsum[r];
        s += __shfl_xor(s, 1);
        s += __shfl_xor(s, 2);
        s += __shfl_xor(s, 4);
        s += __shfl_xor(s, 8);
        rowsum[r] = 1.0f / s;
    }
    __syncthreads();
#pragma unroll
    for (int nf = 0; nf < 4; nf++)
#pragma unroll
        for (int r = 0; r < 4; r++) {
            int n = nf * 16 + llo;
            int cl = w * 16 + lhi * 4 + r;
            Tlds[n][cl] = (bf16)(accY[nf][r] * rowsum[r]);
        }
    __syncthreads();
#pragma unroll
    for (int rr = 0; rr < 7; rr++) {
        int row = rr * 8 + w;
        if (row < NPIX) {
            int i = row / 7, j = row % 7;
            int sp = (i + 1) * 9 + (j + 1);
            int col2 = tid & 63;
            uint32_t val = *(const uint32_t*)&Tlds[row][col2 * 2];
            *(uint32_t*)(YpT + ((size_t)b * 81 + sp) * CC + cblk * 128 + col2 * 2) = val;
        }
    }
}

// ---------- conv GEMM: 256x256, BK=64, per-phase counted-vmcnt pipeline (R11, best) ----------
#define CONV_BARRIER() do { __builtin_amdgcn_sched_barrier(0); \
    __builtin_amdgcn_s_barrier(); __builtin_amdgcn_sched_barrier(0); } while (0)
#define CONV_VMW(n) asm volatile("s_waitcnt vmcnt(" #n ")" ::: "memory")

#define STAGE_HALF(bufOff, t, kh) do {                                         \
    uint32_t kt_ = z * 72u + (uint32_t)(t);                                    \
    uint32_t tap_ = kt_ >> 5, ci0_ = (kt_ & 31u) << 6;                         \
    int tapoff_ = (int)(tap_ / 3u) * 9 + (int)(tap_ % 3u) - 10;                \
    uint32_t kA_ = (uint32_t)(t) * 64u + (uint32_t)(kh) * 32u;                 \
    _Pragma("unroll")                                                          \
    for (int i_ = 0; i_ < 2; i_++) {                                           \
        GLOAD_LDS(srcA[i_] + kA_,                                              \
                  smem + (bufOff) + (kh) * 16384 + i_ * 8192 + tid * 16);      \
        GLOAD_LDS(srcB[i_] + (int)(ci0_ + (uint32_t)(kh) * 32u) + tapoff_ * 2048, \
                  smem + (bufOff) + 32768 + (kh) * 16384 + i_ * 8192 + tid * 16); \
    }                                                                          \
} while (0)

#define CONV_PHASE(bufOff, kk, GATE, STAGE_STMT) do {                          \
    CONV_VMW(GATE);                                                            \
    CONV_BARRIER();                                                            \
    bf16x8 af[8], bfr[4];                                                      \
    _Pragma("unroll")                                                          \
    for (int f = 0; f < 8; f++)                                                \
        af[f] = *(const bf16x8*)(smem + (bufOff) + (kk) * 16384 + offA[f]);    \
    _Pragma("unroll")                                                          \
    for (int f = 0; f < 4; f++)                                                \
        bfr[f] = *(const bf16x8*)(smem + (bufOff) + 32768 + (kk) * 16384 + offB[f]); \
    STAGE_STMT;                                                                \
    asm volatile("s_waitcnt lgkmcnt(0)" ::: "memory");                         \
    __builtin_amdgcn_sched_barrier(0);                                         \
    __builtin_amdgcn_s_setprio(1);                                             \
    _Pragma("unroll")                                                          \
    for (int fm = 0; fm < 8; fm++)                                             \
        _Pragma("unroll")                                                      \
        for (int fn = 0; fn < 4; fn++)                                         \
            acc[fm][fn] = MFMA(af[fm], bfr[fn], acc[fm][fn]);                  \
    __builtin_amdgcn_s_setprio(0);                                             \
    __builtin_amdgcn_sched_barrier(0);                                         \
} while (0)

__global__ __launch_bounds__(512, 2) void conv_kernel(
    const bf16* __restrict__ Wr, const bf16* __restrict__ YpT, float* __restrict__ partials)
{
    extern __shared__ __align__(16) char smem[];
    const int tid = threadIdx.x;
    const int w = tid >> 6, l = tid & 63;
    const int lhi = l >> 4, llo = l & 15;
    const int wm = w >> 2, wn = w & 3;           // wave owns 128co x 64n

    uint32_t g = blockIdx.x;
    uint32_t xcd = g & 7u, inner = g >> 3;       // inner in [0,28)
    uint32_t pairIdx = xcd * 4u + inner / 7u;    // [0,32): (z,mt) grouped per XCD
    uint32_t nt = inner % 7u;
    uint32_t z = pairIdx >> 3, mt = pairIdx & 7u;

    // staging source (pre-swizzled to match read swizzle slot ^ ((row>>1)&3))
    uint32_t rowLoc = tid >> 2;                  // [0,128)
    uint32_t slot = tid & 3u;
    const bf16* srcA[2];
    const bf16* srcB[2];
#pragma unroll
    for (int i = 0; i < 2; i++) {
        uint32_t row = (uint32_t)i * 128u + rowLoc;
        uint32_t swz = (uint32_t)((slot ^ ((row >> 1) & 3u)) << 3);
        srcA[i] = Wr + (size_t)(mt * 256u + row) * K9 + (size_t)z * 4608u + swz;
        uint32_t n = nt * 256u + row;
        uint32_t rowIdx;
        if (n < 1568u) {
            uint32_t b = n / 49u, p = n % 49u;
            uint32_t i2 = p / 7u, j2 = p % 7u;
            rowIdx = b * 81u + (i2 + 1u) * 9u + (j2 + 1u);
        } else rowIdx = 2602u;
        srcB[i] = YpT + (size_t)rowIdx * 2048u + swz;
    }

    // ds_read fragment offsets (swizzled, loop-invariant)
    uint32_t offA[8], offB[4];
#pragma unroll
    for (int f = 0; f < 8; f++) {
        uint32_t r = (uint32_t)(wm * 128 + f * 16 + llo);
        offA[f] = r * 64u + (uint32_t)(((uint32_t)lhi ^ ((r >> 1) & 3u)) << 4);
    }
#pragma unroll
    for (int f = 0; f < 4; f++) {
        uint32_t r = (uint32_t)(wn * 64 + f * 16 + llo);
        offB[f] = r * 64u + (uint32_t)(((uint32_t)lhi ^ ((r >> 1) & 3u)) << 4);
    }

    f32x4 acc[8][4];
#pragma unroll
    for (int fm = 0; fm < 8; fm++)
#pragma unroll
        for (int fn = 0; fn < 4; fn++) acc[fm][fn] = (f32x4){0, 0, 0, 0};

    // prologue: T0.k0, T0.k1 -> buf0; T1.k0 -> buf1   (12 loads/thread)
    STAGE_HALF(0, 0, 0);
    STAGE_HALF(0, 0, 1);
    STAGE_HALF(65536, 1, 0);

    for (int it = 0; it < 35; ++it) {
        const int t0 = it * 2;
        CONV_PHASE(0,     0, 8, STAGE_HALF(65536, t0 + 1, 1));
        CONV_PHASE(0,     1, 8, STAGE_HALF(0,     t0 + 2, 0));
        CONV_PHASE(65536, 0, 8, STAGE_HALF(0,     t0 + 2, 1));
        CONV_PHASE(65536, 1, 8, STAGE_HALF(65536, t0 + 3, 0));
    }
    // peeled final iteration (T70 buf0, T71 buf1)
    CONV_PHASE(0,     0, 8, STAGE_HALF(65536, 71, 1));
    CONV_PHASE(0,     1, 8, (void)0);
    CONV_PHASE(65536, 0, 4, (void)0);
    CONV_PHASE(65536, 1, 0, (void)0);

    float* pz = partials + (size_t)z * 2048u * NP;
    uint32_t co0 = mt * 256u + (uint32_t)(wm * 128 + lhi * 4);
    uint32_t n0 = nt * 256u + (uint32_t)(wn * 64 + llo);
#pragma unroll
    for (int fm = 0; fm < 8; fm++)
#pragma unroll
        for (int fn = 0; fn < 4; fn++)
#pragma unroll
            for (int r = 0; r < 4; r++)
                pz[(size_t)(co0 + fm * 16u + r) * NP + (n0 + fn * 16u)] = acc[fm][fn][r];
}

// ---------- reduce: out = sum_z partials + bias + residual ----------
__global__ void reduce_kernel(const float* __restrict__ partials, const float* __restrict__ x,
                              const float* __restrict__ cb, float* __restrict__ out)
{
    uint32_t idx = blockIdx.x * 256u + threadIdx.x;
    uint32_t p = idx % 49u;
    uint32_t c = (idx / 49u) & 2047u;
    uint32_t b = idx / (49u * 2048u);
    uint32_t n = b * 49u + p;
    size_t base = (size_t)c * NP + n;
    float s = cb[c] + x[idx];
#pragma unroll
    for (int zz = 0; zz < CONV_SPLITK; zz++) s += partials[(size_t)zz * 2048u * NP + base];
    out[idx] = s;
}

extern "C" void kernel_launch(void* const* d_in, const int* in_sizes, int n_in,
                              void* d_out, int out_size, void* d_ws, size_t ws_size,
                              hipStream_t stream) {
    (void)in_sizes; (void)n_in; (void)out_size; (void)ws_size;
    const float* x = (const float*)d_in[0];
    const float* cw = (const float*)d_in[1];
    const float* cb = (const float*)d_in[2];
    float* out = (float*)d_out;
    char* ws = (char*)d_ws;

    bf16* xb   = (bf16*)(ws);                    //   8,388,608 B
    bf16* xbT  = (bf16*)(ws + 8388608);          //   8,388,608 B
    bf16* Wr   = (bf16*)(ws + 16777216);         //  75,497,472 B
    bf16* YpT  = (bf16*)(ws + 92274688);         //  10,747,904 B
    float* partials = (float*)(ws + 103022592);  //  58,720,256 B (total 161,742,848)

    hipFuncSetAttribute((const void*)conv_kernel,
                        hipFuncAttributeMaxDynamicSharedMemorySize, 131072);

    prep_fused_kernel<<<512, 256, 0, stream>>>(x, xb, xbT);
    castw_kernel<<<4096, 256, 0, stream>>>(cw, Wr);
    attn_kernel<<<512, 512, 0, stream>>>(xb, xbT, YpT);
    conv_kernel<<<224, 512, 131072, stream>>>(Wr, YpT, partials);
    reduce_kernel<<<12544, 256, 0, stream>>>(partials, x, cb, out);
}